// Round 2
// baseline (3999.504 us; speedup 1.0000x reference)
//
#include <hip/hip_runtime.h>
#include <cstdint>
#include <cfloat>

#define IN_DIM 768
#define HID    1024
#define KSEL   20
#define NCAND  32

// ---------------- K0: transpose W_dec [768][1024] -> WdT [1024][768] ----------------
__global__ void k_transpose(const float* __restrict__ Wd, float* __restrict__ WdT) {
    __shared__ float tile[32][33];
    const int j0 = blockIdx.x * 32;       // along HID
    const int i0 = blockIdx.y * 32;       // along IN_DIM
    const int tx = threadIdx.x;           // 0..31
    const int ty = threadIdx.y;           // 0..7
#pragma unroll
    for (int r = 0; r < 4; ++r)
        tile[ty + r * 8][tx] = Wd[(size_t)(i0 + ty + r * 8) * HID + (j0 + tx)];
    __syncthreads();
#pragma unroll
    for (int r = 0; r < 4; ++r)
        WdT[(size_t)(j0 + ty + r * 8) * IN_DIM + (i0 + tx)] = tile[tx][ty + r * 8];
}

// ---------------- K1: fp32 encode GEMM  h = relu(x @ We^T + be) ----------------
__global__ __launch_bounds__(256, 2) void k_encode(
    const float* __restrict__ x, const float* __restrict__ We,
    const float* __restrict__ be, float* __restrict__ h)
{
    __shared__ float lx[16][132];
    __shared__ float lw[16][132];
    const int t  = threadIdx.x;
    const int tx = t & 15;
    const int ty = t >> 4;
    const int bn = blockIdx.x * 128;
    const int bm = blockIdx.y * 128;

    float acc[8][8];
#pragma unroll
    for (int r = 0; r < 8; ++r)
#pragma unroll
        for (int c = 0; c < 8; ++c) acc[r][c] = 0.f;

    const int sk = t & 15;
    const int sm = t >> 4;

    for (int kt = 0; kt < IN_DIM; kt += 16) {
        __syncthreads();
#pragma unroll
        for (int p = 0; p < 8; ++p) {
            const int m = sm + p * 16;
            lx[sk][m] = x [(size_t)(bm + m) * IN_DIM + (kt + sk)];
            lw[sk][m] = We[(size_t)(bn + m) * IN_DIM + (kt + sk)];
        }
        __syncthreads();
#pragma unroll
        for (int kk = 0; kk < 16; ++kk) {
            const float4 xa = *(const float4*)&lx[kk][ty * 8];
            const float4 xb = *(const float4*)&lx[kk][ty * 8 + 4];
            const float4 wa = *(const float4*)&lw[kk][tx * 4];
            const float4 wb = *(const float4*)&lw[kk][tx * 4 + 64];
            const float xf[8] = {xa.x, xa.y, xa.z, xa.w, xb.x, xb.y, xb.z, xb.w};
            const float wf[8] = {wa.x, wa.y, wa.z, wa.w, wb.x, wb.y, wb.z, wb.w};
#pragma unroll
            for (int r = 0; r < 8; ++r)
#pragma unroll
                for (int c = 0; c < 8; ++c)
                    acc[r][c] = fmaf(xf[r], wf[c], acc[r][c]);
        }
    }

    float bva[4], bvb[4];
#pragma unroll
    for (int c = 0; c < 4; ++c) {
        bva[c] = be[bn + tx * 4 + c];
        bvb[c] = be[bn + 64 + tx * 4 + c];
    }
#pragma unroll
    for (int r = 0; r < 8; ++r) {
        const size_t row = (size_t)(bm + ty * 8 + r) * HID;
        float4 o1, o2;
        o1.x = fmaxf(acc[r][0] + bva[0], 0.f);
        o1.y = fmaxf(acc[r][1] + bva[1], 0.f);
        o1.z = fmaxf(acc[r][2] + bva[2], 0.f);
        o1.w = fmaxf(acc[r][3] + bva[3], 0.f);
        o2.x = fmaxf(acc[r][4] + bvb[0], 0.f);
        o2.y = fmaxf(acc[r][5] + bvb[1], 0.f);
        o2.z = fmaxf(acc[r][6] + bvb[2], 0.f);
        o2.w = fmaxf(acc[r][7] + bvb[3], 0.f);
        *(float4*)&h[row + bn + tx * 4]      = o1;
        *(float4*)&h[row + bn + 64 + tx * 4] = o2;
    }
}

// ---------------- K2: top-32 fp32 candidates -> f64 refine -> top-20 -> mask + decode ----------------
__global__ __launch_bounds__(256) void k_topk_decode(
    float* __restrict__ h,
    const float* __restrict__ x,  const float* __restrict__ We,
    const float* __restrict__ be,
    const float* __restrict__ WdT, const float* __restrict__ Wd,
    const float* __restrict__ bd,
    float* __restrict__ recon, const int useT)
{
    const int b    = blockIdx.x;
    const int t    = threadIdx.x;
    const int lane = t & 63;
    const int wid  = t >> 6;
    float* hrow = h + (size_t)b * HID;

    __shared__ float  swv[4];
    __shared__ int    swi[4];
    __shared__ float  fselv[NCAND];   // fp32 h value of candidate
    __shared__ int    cj[NCAND];      // original index of candidate
    __shared__ double cval[NCAND];    // f64 refined value
    __shared__ float  sel20v[KSEL];
    __shared__ int    sel20j[KSEL];
    __shared__ float  sx[IN_DIM];     // x row for refinement

    // stage x row (also used by phase B)
    sx[t]       = x[(size_t)b * IN_DIM + t];
    sx[t + 256] = x[(size_t)b * IN_DIM + t + 256];
    sx[t + 512] = x[(size_t)b * IN_DIM + t + 512];

    const float4 v4 = *(const float4*)&hrow[t * 4];
    float orig[4] = {v4.x, v4.y, v4.z, v4.w};
    float work[4] = {v4.x, v4.y, v4.z, v4.w};

    // -------- Phase A: extract top-32 by fp32 value (tie -> lower index) --------
    for (int s = 0; s < NCAND; ++s) {
        float bv = work[0]; int bi = t * 4;
#pragma unroll
        for (int i = 1; i < 4; ++i)
            if (work[i] > bv) { bv = work[i]; bi = t * 4 + i; }
#pragma unroll
        for (int off = 32; off > 0; off >>= 1) {
            const float ov = __shfl_xor(bv, off);
            const int   oi = __shfl_xor(bi, off);
            if (ov > bv || (ov == bv && oi < bi)) { bv = ov; bi = oi; }
        }
        if (lane == 0) { swv[wid] = bv; swi[wid] = bi; }
        __syncthreads();
        float wv = swv[0]; int wj = swi[0];
#pragma unroll
        for (int w = 1; w < 4; ++w)
            if (swv[w] > wv || (swv[w] == wv && swi[w] < wj)) { wv = swv[w]; wj = swi[w]; }
        if (t == 0) { fselv[s] = wv; cj[s] = wj; }
        if ((wj >> 2) == t) work[wj & 3] = -1.f;
        __syncthreads();
    }

    // -------- Phase B: f64 recompute of the 32 candidate dots --------
    {
        const int tid8 = t & 7;
        const int c    = t >> 3;           // candidate 0..31
        const int j    = cj[c];
        const float* wr = We + (size_t)j * IN_DIM;
        double s = 0.0;
#pragma unroll 8
        for (int m = 0; m < IN_DIM / 8; ++m) {
            const int k = tid8 + (m << 3);
            s = fma((double)sx[k], (double)wr[k], s);
        }
#pragma unroll
        for (int off = 4; off > 0; off >>= 1) s += __shfl_xor(s, off);
        if (tid8 == 0) {
            double v = s + (double)be[j];
            cval[c] = v > 0.0 ? v : 0.0;   // relu, matching ref order
        }
    }
    __syncthreads();

    // -------- Phase C: top-20 of 32 by f64 value (tie -> lower index), wave 0 only --------
    if (t < 64) {
        double val = (t < NCAND) ? cval[t] : -DBL_MAX;
        const int myj = (t < NCAND) ? cj[t] : 0x7fffffff;
        for (int s = 0; s < KSEL; ++s) {
            double bv = val; int bj = myj; int bc = t;
#pragma unroll
            for (int off = 1; off < 64; off <<= 1) {
                const double ov = __shfl_xor(bv, off);
                const int    oj = __shfl_xor(bj, off);
                const int    oc = __shfl_xor(bc, off);
                if (ov > bv || (ov == bv && oj < bj)) { bv = ov; bj = oj; bc = oc; }
            }
            if (t == 0) { sel20v[s] = fselv[bc]; sel20j[s] = bj; }
            if (t == bc) val = -DBL_MAX;
        }
    }
    __syncthreads();

    // -------- Phase D: mask h row by membership in sel20 --------
    float4 o;
    float ov[4] = {0.f, 0.f, 0.f, 0.f};
#pragma unroll
    for (int i = 0; i < 4; ++i) {
        const int idx = t * 4 + i;
        bool keep = false;
#pragma unroll
        for (int s = 0; s < KSEL; ++s) keep |= (sel20j[s] == idx);
        ov[i] = keep ? orig[i] : 0.f;
    }
    o.x = ov[0]; o.y = ov[1]; o.z = ov[2]; o.w = ov[3];
    *(float4*)&hrow[t * 4] = o;

    // -------- sparse decode --------
    float a0 = 0.f, a1 = 0.f, a2 = 0.f;
    if (useT) {
        for (int s = 0; s < KSEL; ++s) {
            const float v = sel20v[s];
            const float* wr = WdT + (size_t)sel20j[s] * IN_DIM;
            a0 = fmaf(v, wr[t], a0);
            a1 = fmaf(v, wr[t + 256], a1);
            a2 = fmaf(v, wr[t + 512], a2);
        }
    } else {
        for (int s = 0; s < KSEL; ++s) {
            const float v = sel20v[s];
            const int j = sel20j[s];
            a0 = fmaf(v, Wd[(size_t)t * HID + j], a0);
            a1 = fmaf(v, Wd[(size_t)(t + 256) * HID + j], a1);
            a2 = fmaf(v, Wd[(size_t)(t + 512) * HID + j], a2);
        }
    }
    float* rrow = recon + (size_t)b * IN_DIM;
    rrow[t]       = a0 + bd[t];
    rrow[t + 256] = a1 + bd[t + 256];
    rrow[t + 512] = a2 + bd[t + 512];
}

extern "C" void kernel_launch(void* const* d_in, const int* in_sizes, int n_in,
                              void* d_out, int out_size, void* d_ws, size_t ws_size,
                              hipStream_t stream)
{
    const float* x  = (const float*)d_in[0];
    const float* We = (const float*)d_in[1];
    const float* be = (const float*)d_in[2];
    const float* Wd = (const float*)d_in[3];
    const float* bd = (const float*)d_in[4];
    const int batch = in_sizes[0] / IN_DIM;   // 65536

    float* recon = (float*)d_out;
    float* h     = (float*)d_out + (size_t)batch * IN_DIM;

    float* WdT = (float*)d_ws;
    const int useT = (ws_size >= (size_t)IN_DIM * HID * sizeof(float)) ? 1 : 0;

    if (useT) {
        dim3 g(HID / 32, IN_DIM / 32), blk(32, 8);
        k_transpose<<<g, blk, 0, stream>>>(Wd, WdT);
    }
    {
        dim3 g(HID / 128, batch / 128), blk(256);
        k_encode<<<g, blk, 0, stream>>>(x, We, be, h);
    }
    k_topk_decode<<<batch, 256, 0, stream>>>(h, x, We, be, WdT, Wd, bd, recon, useT);
}

// Round 3
// 1991.188 us; speedup vs baseline: 2.0086x; 2.0086x over previous
//
#include <hip/hip_runtime.h>
#include <cstdint>
#include <cfloat>

#define IN_DIM 768
#define HID    1024
#define KSEL   20
#define MAXC   64
#define TARGET 24u

// ---------------- K0: transpose W_dec [768][1024] -> WdT [1024][768] ----------------
__global__ void k_transpose(const float* __restrict__ Wd, float* __restrict__ WdT) {
    __shared__ float tile[32][33];
    const int j0 = blockIdx.x * 32;
    const int i0 = blockIdx.y * 32;
    const int tx = threadIdx.x;
    const int ty = threadIdx.y;
#pragma unroll
    for (int r = 0; r < 4; ++r)
        tile[ty + r * 8][tx] = Wd[(size_t)(i0 + ty + r * 8) * HID + (j0 + tx)];
    __syncthreads();
#pragma unroll
    for (int r = 0; r < 4; ++r)
        WdT[(size_t)(j0 + ty + r * 8) * IN_DIM + (i0 + tx)] = tile[tx][ty + r * 8];
}

// ---------------- K1: fp32 encode GEMM  h = relu(x @ We^T + be) ----------------
__global__ __launch_bounds__(256, 2) void k_encode(
    const float* __restrict__ x, const float* __restrict__ We,
    const float* __restrict__ be, float* __restrict__ h)
{
    __shared__ float lx[16][132];
    __shared__ float lw[16][132];
    const int t  = threadIdx.x;
    const int tx = t & 15;
    const int ty = t >> 4;
    const int bn = blockIdx.x * 128;
    const int bm = blockIdx.y * 128;

    float acc[8][8];
#pragma unroll
    for (int r = 0; r < 8; ++r)
#pragma unroll
        for (int c = 0; c < 8; ++c) acc[r][c] = 0.f;

    const int sk = t & 15;
    const int sm = t >> 4;

    for (int kt = 0; kt < IN_DIM; kt += 16) {
        __syncthreads();
#pragma unroll
        for (int p = 0; p < 8; ++p) {
            const int m = sm + p * 16;
            lx[sk][m] = x [(size_t)(bm + m) * IN_DIM + (kt + sk)];
            lw[sk][m] = We[(size_t)(bn + m) * IN_DIM + (kt + sk)];
        }
        __syncthreads();
#pragma unroll
        for (int kk = 0; kk < 16; ++kk) {
            const float4 xa = *(const float4*)&lx[kk][ty * 8];
            const float4 xb = *(const float4*)&lx[kk][ty * 8 + 4];
            const float4 wa = *(const float4*)&lw[kk][tx * 4];
            const float4 wb = *(const float4*)&lw[kk][tx * 4 + 64];
            const float xf[8] = {xa.x, xa.y, xa.z, xa.w, xb.x, xb.y, xb.z, xb.w};
            const float wf[8] = {wa.x, wa.y, wa.z, wa.w, wb.x, wb.y, wb.z, wb.w};
#pragma unroll
            for (int r = 0; r < 8; ++r)
#pragma unroll
                for (int c = 0; c < 8; ++c)
                    acc[r][c] = fmaf(xf[r], wf[c], acc[r][c]);
        }
    }

    float bva[4], bvb[4];
#pragma unroll
    for (int c = 0; c < 4; ++c) {
        bva[c] = be[bn + tx * 4 + c];
        bvb[c] = be[bn + 64 + tx * 4 + c];
    }
#pragma unroll
    for (int r = 0; r < 8; ++r) {
        const size_t row = (size_t)(bm + ty * 8 + r) * HID;
        float4 o1, o2;
        o1.x = fmaxf(acc[r][0] + bva[0], 0.f);
        o1.y = fmaxf(acc[r][1] + bva[1], 0.f);
        o1.z = fmaxf(acc[r][2] + bva[2], 0.f);
        o1.w = fmaxf(acc[r][3] + bva[3], 0.f);
        o2.x = fmaxf(acc[r][4] + bvb[0], 0.f);
        o2.y = fmaxf(acc[r][5] + bvb[1], 0.f);
        o2.z = fmaxf(acc[r][6] + bvb[2], 0.f);
        o2.w = fmaxf(acc[r][7] + bvb[3], 0.f);
        *(float4*)&h[row + bn + tx * 4]      = o1;
        *(float4*)&h[row + bn + 64 + tx * 4] = o2;
    }
}

// ---------------- K2: radix-threshold top-k -> f64 refine -> rank-select -> mask + decode ----------------
__global__ __launch_bounds__(256) void k_topk_decode(
    float* __restrict__ h,
    const float* __restrict__ x,  const float* __restrict__ We,
    const float* __restrict__ be,
    const float* __restrict__ WdT, const float* __restrict__ bd,
    float* __restrict__ recon)
{
    const int b = blockIdx.x;
    const int t = threadIdx.x;
    float* hrow = h + (size_t)b * HID;

    __shared__ double sxd[IN_DIM];     // x row as f64
    __shared__ uint   hist[256];
    __shared__ uint   bc_prefix, bc_target, bc_done;
    __shared__ uint   scount;
    __shared__ float  cv[MAXC];
    __shared__ int    cjj[MAXC];
    __shared__ double cval[MAXC];
    __shared__ uint   flagw[256];      // 1024 flag bytes
    __shared__ float  sel20v[KSEL];
    __shared__ int    sel20j[KSEL];

    // stage x row as f64 (used by refine)
    sxd[t]       = (double)x[(size_t)b * IN_DIM + t];
    sxd[t + 256] = (double)x[(size_t)b * IN_DIM + t + 256];
    sxd[t + 512] = (double)x[(size_t)b * IN_DIM + t + 512];
    if (t == 0) scount = 0;

    const float4 v4 = *(const float4*)&hrow[t * 4];
    const float vals[4] = {v4.x, v4.y, v4.z, v4.w};
    uint keys[4];
#pragma unroll
    for (int i = 0; i < 4; ++i) keys[i] = __float_as_uint(vals[i]);  // h >= 0 -> monotone

    // -------- Phase A: radix threshold so that 24 <= count(key >= prefix) <= 64 --------
    uint prefix = 0, target = TARGET, done = 0;
    for (int level = 0; level < 4; ++level) {
        const int  shift = 24 - 8 * level;
        const uint pmask = (level == 0) ? 0u : (0xFFFFFFFFu << (shift + 8));
        hist[t] = 0;
        __syncthreads();
#pragma unroll
        for (int i = 0; i < 4; ++i)
            if ((keys[i] & pmask) == prefix)
                atomicAdd(&hist[(keys[i] >> shift) & 0xFF], 1u);
        __syncthreads();
        if (t < 64) {
            const int l = t;
            const uint c0 = hist[255 - 4 * l];
            const uint c1 = hist[254 - 4 * l];
            const uint c2 = hist[253 - 4 * l];
            const uint c3 = hist[252 - 4 * l];
            const uint sl = c0 + c1 + c2 + c3;
            uint inc = sl;
#pragma unroll
            for (int off = 1; off < 64; off <<= 1) {
                const uint o = __shfl_up(inc, off);
                if (l >= off) inc += o;
            }
            const uint excl = inc - sl;
            const uint cum0 = excl + c0, cum1 = cum0 + c1, cum2 = cum1 + c2, cum3 = cum2 + c3;
            const bool cross = (excl < target) && (cum3 >= target);
            int which; uint cumGE, cumAbove;
            if      (cum0 >= target) { which = 0; cumGE = cum0; cumAbove = excl; }
            else if (cum1 >= target) { which = 1; cumGE = cum1; cumAbove = cum0; }
            else if (cum2 >= target) { which = 2; cumGE = cum2; cumAbove = cum1; }
            else                     { which = 3; cumGE = cum3; cumAbove = cum2; }
            int pb = 255 - 4 * l - which;
            const unsigned long long bal = __ballot(cross);
            const int src = __ffsll(bal) - 1;
            pb       = __shfl(pb, src);
            cumGE    = (uint)__shfl((int)cumGE, src);
            cumAbove = (uint)__shfl((int)cumAbove, src);
            if (l == 0) {
                bc_prefix = prefix | ((uint)pb << shift);
                bc_target = target - cumAbove;
                // total candidates = (TARGET - target) + cumGE
                bc_done   = ((TARGET - target) + cumGE <= MAXC) ? 1u : 0u;
            }
        }
        __syncthreads();
        prefix = bc_prefix; target = bc_target; done = bc_done;
        if (done) break;
    }

    // -------- Phase B: compact candidates (key >= prefix) --------
#pragma unroll
    for (int i = 0; i < 4; ++i) {
        if (keys[i] >= prefix) {
            const uint p = atomicAdd(&scount, 1u);
            if (p < MAXC) { cv[p] = vals[i]; cjj[p] = t * 4 + i; }
        }
    }
    flagw[t] = 0;
    __syncthreads();
    const int n = (int)min(scount, (uint)MAXC);

    // -------- Phase C: f64 refine of candidate dots (4 threads per candidate) --------
    {
        const int c  = t >> 2;
        const int l4 = t & 3;
        if (c < n) {
            const int j = cjj[c];
            const float* wr = We + (size_t)j * IN_DIM;
            double s0 = 0.0, s1 = 0.0, s2 = 0.0, s3 = 0.0;
#pragma unroll 4
            for (int m = 0; m < 48; ++m) {
                const int k = l4 * 4 + 16 * m;
                const float4 w4 = *(const float4*)&wr[k];
                s0 = fma((double)w4.x, sxd[k],     s0);
                s1 = fma((double)w4.y, sxd[k + 1], s1);
                s2 = fma((double)w4.z, sxd[k + 2], s2);
                s3 = fma((double)w4.w, sxd[k + 3], s3);
            }
            double s = (s0 + s1) + (s2 + s3);
            s += __shfl_xor(s, 1);
            s += __shfl_xor(s, 2);
            if (l4 == 0) {
                const double v = s + (double)be[j];
                cval[c] = v > 0.0 ? v : 0.0;
            }
        }
    }
    __syncthreads();

    // -------- Phase D: rank-based top-20 (wave 0), set flags + sel list --------
    if (t < 64) {
        const double myv = (t < n) ? cval[t] : -1.0;
        const int    myj = (t < n) ? cjj[t]  : 0x7fffffff;
        int rank = 0;
        for (int o = 0; o < n; ++o) {
            const double ov = cval[o];
            const int    oj = cjj[o];
            rank += (ov > myv || (ov == myv && oj < myj)) ? 1 : 0;
        }
        if (t < n && rank < KSEL) {
            sel20v[rank] = (float)myv;
            sel20j[rank] = myj;
            ((unsigned char*)flagw)[myj] = 1;
        }
    }
    __syncthreads();

    // -------- Phase E: masked h write --------
    {
        const uint fw = flagw[t];
        float4 o;
        o.x = (fw & 0x000000FFu) ? vals[0] : 0.f;
        o.y = (fw & 0x0000FF00u) ? vals[1] : 0.f;
        o.z = (fw & 0x00FF0000u) ? vals[2] : 0.f;
        o.w = (fw & 0xFF000000u) ? vals[3] : 0.f;
        *(float4*)&hrow[t * 4] = o;
    }

    // -------- Phase F: sparse decode --------
    float a0 = 0.f, a1 = 0.f, a2 = 0.f;
#pragma unroll 4
    for (int s = 0; s < KSEL; ++s) {
        const float v = sel20v[s];
        const float* wr = WdT + (size_t)sel20j[s] * IN_DIM;
        a0 = fmaf(v, wr[t], a0);
        a1 = fmaf(v, wr[t + 256], a1);
        a2 = fmaf(v, wr[t + 512], a2);
    }
    float* rrow = recon + (size_t)b * IN_DIM;
    rrow[t]       = a0 + bd[t];
    rrow[t + 256] = a1 + bd[t + 256];
    rrow[t + 512] = a2 + bd[t + 512];
}

extern "C" void kernel_launch(void* const* d_in, const int* in_sizes, int n_in,
                              void* d_out, int out_size, void* d_ws, size_t ws_size,
                              hipStream_t stream)
{
    const float* x  = (const float*)d_in[0];
    const float* We = (const float*)d_in[1];
    const float* be = (const float*)d_in[2];
    const float* Wd = (const float*)d_in[3];
    const float* bd = (const float*)d_in[4];
    const int batch = in_sizes[0] / IN_DIM;   // 65536

    float* recon = (float*)d_out;
    float* h     = (float*)d_out + (size_t)batch * IN_DIM;

    float* WdT = (float*)d_ws;   // 3 MB, ws is large enough

    {
        dim3 g(HID / 32, IN_DIM / 32), blk(32, 8);
        k_transpose<<<g, blk, 0, stream>>>(Wd, WdT);
    }
    {
        dim3 g(HID / 128, batch / 128), blk(256);
        k_encode<<<g, blk, 0, stream>>>(x, We, be, h);
    }
    k_topk_decode<<<batch, 256, 0, stream>>>(h, x, We, be, WdT, bd, recon);
}

// Round 4
// 762.426 us; speedup vs baseline: 5.2458x; 2.6116x over previous
//
#include <hip/hip_runtime.h>
#include <cstdint>
#include <cfloat>

#define IN_DIM 768
#define HID    1024
#define KSEL   20
#define MAXC   64
#define TARGET 24u
#define WSCALE 4096.0f
#define INV_WSCALE (1.0f / 4096.0f)
#define DELTA  3e-5f

typedef _Float16 f16x8 __attribute__((ext_vector_type(8)));
typedef float    f32x4 __attribute__((ext_vector_type(4)));

__device__ __forceinline__ void gload_lds16(const void* g, void* l) {
    __builtin_amdgcn_global_load_lds(
        (const __attribute__((address_space(1))) uint32_t*)g,
        (__attribute__((address_space(3))) uint32_t*)l, 16, 0, 0);
}

// ---------------- K0: transpose W_dec [768][1024] -> WdT [1024][768] ----------------
__global__ void k_transpose(const float* __restrict__ Wd, float* __restrict__ WdT) {
    __shared__ float tile[32][33];
    const int j0 = blockIdx.x * 32;
    const int i0 = blockIdx.y * 32;
    const int tx = threadIdx.x;
    const int ty = threadIdx.y;
#pragma unroll
    for (int r = 0; r < 4; ++r)
        tile[ty + r * 8][tx] = Wd[(size_t)(i0 + ty + r * 8) * HID + (j0 + tx)];
    __syncthreads();
#pragma unroll
    for (int r = 0; r < 4; ++r)
        WdT[(size_t)(j0 + ty + r * 8) * IN_DIM + (i0 + tx)] = tile[tx][ty + r * 8];
}

// ---------------- split kernels: fp32 -> fp16 (W scaled by 4096) ----------------
__global__ __launch_bounds__(256) void k_split_x(const float* __restrict__ x,
                                                 _Float16* __restrict__ xh) {
    const size_t base = ((size_t)blockIdx.x * 256 + threadIdx.x) * 8;
    const float4 a = *(const float4*)(x + base);
    const float4 b = *(const float4*)(x + base + 4);
    f16x8 o;
    o[0] = (_Float16)a.x; o[1] = (_Float16)a.y; o[2] = (_Float16)a.z; o[3] = (_Float16)a.w;
    o[4] = (_Float16)b.x; o[5] = (_Float16)b.y; o[6] = (_Float16)b.z; o[7] = (_Float16)b.w;
    *(f16x8*)(xh + base) = o;
}

__global__ __launch_bounds__(256) void k_split_w(const float* __restrict__ w,
                                                 _Float16* __restrict__ wh) {
    const size_t base = ((size_t)blockIdx.x * 256 + threadIdx.x) * 8;
    const float4 a = *(const float4*)(w + base);
    const float4 b = *(const float4*)(w + base + 4);
    f16x8 o;
    o[0] = (_Float16)(a.x * WSCALE); o[1] = (_Float16)(a.y * WSCALE);
    o[2] = (_Float16)(a.z * WSCALE); o[3] = (_Float16)(a.w * WSCALE);
    o[4] = (_Float16)(b.x * WSCALE); o[5] = (_Float16)(b.y * WSCALE);
    o[6] = (_Float16)(b.z * WSCALE); o[7] = (_Float16)(b.w * WSCALE);
    *(f16x8*)(wh + base) = o;
}

// ---------------- K1: fp16 MFMA encode  h = relu((x16 @ w16^T)/4096 + be) ----------------
// 128x128 tile, BK=64, 4 waves (2x2 of 64x64), 16x16x32 f16 MFMA.
// LDS tiles [128 rows][64 halves=128B]; slot-swizzle s_phys = s_log ^ (row&7)
// applied on BOTH the global staging source and the ds_read side (involution).
__global__ __launch_bounds__(256) void k_encode_f16(
    const _Float16* __restrict__ xh, const _Float16* __restrict__ wh,
    const float* __restrict__ be, float* __restrict__ h)
{
    __shared__ _Float16 lA[128 * 64];   // 16 KB
    __shared__ _Float16 lB[128 * 64];   // 16 KB
    const int t   = threadIdx.x;
    const int wid = t >> 6, l = t & 63;
    const int wm  = (wid >> 1) * 64, wn = (wid & 1) * 64;
    const int bn  = blockIdx.x * 128, bm = blockIdx.y * 128;

    // staging: per issue i, wave covers rows wid*32+i*8 .. +7 (8 rows x 128B = 1KB)
    const int lr = l >> 3;              // row within 8-row group
    const int sl = (l & 7) ^ lr;        // logical slot this lane must fetch
    const _Float16* gA = xh + (size_t)(bm + wid * 32 + lr) * IN_DIM + sl * 8;
    const _Float16* gB = wh + (size_t)(bn + wid * 32 + lr) * IN_DIM + sl * 8;
    char* la0 = (char*)lA + wid * 32 * 128;
    char* lb0 = (char*)lB + wid * 32 * 128;

    f32x4 acc[4][4];
#pragma unroll
    for (int i = 0; i < 4; ++i)
#pragma unroll
        for (int j = 0; j < 4; ++j) acc[i][j] = (f32x4){0.f, 0.f, 0.f, 0.f};

    const int row16 = l & 15, kb = l >> 4;

    for (int kt = 0; kt < IN_DIM; kt += 64) {
        __syncthreads();
#pragma unroll
        for (int i = 0; i < 4; ++i) {
            gload_lds16(gA + (size_t)i * 8 * IN_DIM + kt, la0 + i * 1024);
            gload_lds16(gB + (size_t)i * 8 * IN_DIM + kt, lb0 + i * 1024);
        }
        __syncthreads();   // compiler drains vmcnt before barrier

        f16x8 af[4][2], bf[4][2];
#pragma unroll
        for (int f = 0; f < 4; ++f) {
            const int ra = wm + f * 16 + row16;
            const int pa = kb ^ (ra & 7);
            af[f][0] = *(const f16x8*)((const char*)lA + ra * 128 + pa * 16);
            af[f][1] = *(const f16x8*)((const char*)lA + ra * 128 + (pa ^ 4) * 16);
            const int rb = wn + f * 16 + row16;
            const int pb = kb ^ (rb & 7);
            bf[f][0] = *(const f16x8*)((const char*)lB + rb * 128 + pb * 16);
            bf[f][1] = *(const f16x8*)((const char*)lB + rb * 128 + (pb ^ 4) * 16);
        }
#pragma unroll
        for (int kh = 0; kh < 2; ++kh)
#pragma unroll
            for (int fm = 0; fm < 4; ++fm)
#pragma unroll
                for (int fn = 0; fn < 4; ++fn)
                    acc[fm][fn] = __builtin_amdgcn_mfma_f32_16x16x32_f16(
                        af[fm][kh], bf[fn][kh], acc[fm][fn], 0, 0, 0);
    }

    // epilogue: unscale, +bias, relu, store (C/D: col=lane&15, row=(lane>>4)*4+reg)
    const int col = l & 15, rg = (l >> 4) * 4;
#pragma unroll
    for (int fn = 0; fn < 4; ++fn) {
        const int n = bn + wn + fn * 16 + col;
        const float bias = be[n];
#pragma unroll
        for (int fm = 0; fm < 4; ++fm) {
            const int m0 = bm + wm + fm * 16 + rg;
#pragma unroll
            for (int q = 0; q < 4; ++q)
                h[(size_t)(m0 + q) * HID + n] = fmaxf(fmaf(acc[fm][fn][q], INV_WSCALE, bias), 0.f);
        }
    }
}

// ---------------- K1-fallback: fp32 encode (if ws too small for fp16 path) ----------------
__global__ __launch_bounds__(256, 2) void k_encode(
    const float* __restrict__ x, const float* __restrict__ We,
    const float* __restrict__ be, float* __restrict__ h)
{
    __shared__ float lx[16][132];
    __shared__ float lw[16][132];
    const int t  = threadIdx.x;
    const int tx = t & 15;
    const int ty = t >> 4;
    const int bn = blockIdx.x * 128;
    const int bm = blockIdx.y * 128;

    float acc[8][8];
#pragma unroll
    for (int r = 0; r < 8; ++r)
#pragma unroll
        for (int c = 0; c < 8; ++c) acc[r][c] = 0.f;

    const int sk = t & 15;
    const int sm = t >> 4;

    for (int kt = 0; kt < IN_DIM; kt += 16) {
        __syncthreads();
#pragma unroll
        for (int p = 0; p < 8; ++p) {
            const int m = sm + p * 16;
            lx[sk][m] = x [(size_t)(bm + m) * IN_DIM + (kt + sk)];
            lw[sk][m] = We[(size_t)(bn + m) * IN_DIM + (kt + sk)];
        }
        __syncthreads();
#pragma unroll
        for (int kk = 0; kk < 16; ++kk) {
            const float4 xa = *(const float4*)&lx[kk][ty * 8];
            const float4 xb = *(const float4*)&lx[kk][ty * 8 + 4];
            const float4 wa = *(const float4*)&lw[kk][tx * 4];
            const float4 wb = *(const float4*)&lw[kk][tx * 4 + 64];
            const float xf[8] = {xa.x, xa.y, xa.z, xa.w, xb.x, xb.y, xb.z, xb.w};
            const float wf[8] = {wa.x, wa.y, wa.z, wa.w, wb.x, wb.y, wb.z, wb.w};
#pragma unroll
            for (int r = 0; r < 8; ++r)
#pragma unroll
                for (int c = 0; c < 8; ++c)
                    acc[r][c] = fmaf(xf[r], wf[c], acc[r][c]);
        }
    }
#pragma unroll
    for (int r = 0; r < 8; ++r) {
        const size_t row = (size_t)(bm + ty * 8 + r) * HID;
#pragma unroll
        for (int c = 0; c < 4; ++c) {
            h[row + bn + tx * 4 + c]      = fmaxf(acc[r][c]     + be[bn + tx * 4 + c], 0.f);
            h[row + bn + 64 + tx * 4 + c] = fmaxf(acc[r][c + 4] + be[bn + 64 + tx * 4 + c], 0.f);
        }
    }
}

// ---------------- K2: radix top-k -> lazy f64 refine -> mask + sparse decode ----------------
__global__ __launch_bounds__(256) void k_topk_decode(
    float* __restrict__ h,
    const float* __restrict__ x,  const float* __restrict__ We,
    const float* __restrict__ be,
    const float* __restrict__ WdT, const float* __restrict__ bd,
    float* __restrict__ recon)
{
    const int b = blockIdx.x;
    const int t = threadIdx.x;
    float* hrow = h + (size_t)b * HID;

    __shared__ double sxd[IN_DIM];
    __shared__ uint   hist[256];
    __shared__ uint   bc_prefix, bc_target, bc_done;
    __shared__ uint   scount;
    __shared__ float  cv[MAXC];
    __shared__ int    cjj[MAXC];
    __shared__ double cval[MAXC];
    __shared__ int    crank[MAXC];
    __shared__ uint   flagw[256];
    __shared__ float  sel20v[KSEL];
    __shared__ int    sel20j[KSEL];
    __shared__ float  sh_v20, sh_v21;

    if (t == 0) { scount = 0; sh_v20 = 0.f; sh_v21 = 1e9f; }

    const float4 v4 = *(const float4*)&hrow[t * 4];
    const float vals[4] = {v4.x, v4.y, v4.z, v4.w};
    uint keys[4];
#pragma unroll
    for (int i = 0; i < 4; ++i) keys[i] = __float_as_uint(vals[i]);  // h >= 0 -> monotone

    // -------- Phase A: radix threshold so that 24 <= count(key >= prefix) <= 64 --------
    uint prefix = 0, target = TARGET, done = 0;
    for (int level = 0; level < 4; ++level) {
        const int  shift = 24 - 8 * level;
        const uint pmask = (level == 0) ? 0u : (0xFFFFFFFFu << (shift + 8));
        hist[t] = 0;
        __syncthreads();
#pragma unroll
        for (int i = 0; i < 4; ++i)
            if ((keys[i] & pmask) == prefix)
                atomicAdd(&hist[(keys[i] >> shift) & 0xFF], 1u);
        __syncthreads();
        if (t < 64) {
            const int l = t;
            const uint c0 = hist[255 - 4 * l];
            const uint c1 = hist[254 - 4 * l];
            const uint c2 = hist[253 - 4 * l];
            const uint c3 = hist[252 - 4 * l];
            const uint slc = c0 + c1 + c2 + c3;
            uint inc = slc;
#pragma unroll
            for (int off = 1; off < 64; off <<= 1) {
                const uint o = __shfl_up(inc, off);
                if (l >= off) inc += o;
            }
            const uint excl = inc - slc;
            const uint cum0 = excl + c0, cum1 = cum0 + c1, cum2 = cum1 + c2, cum3 = cum2 + c3;
            const bool cross = (excl < target) && (cum3 >= target);
            int which; uint cumGE, cumAbove;
            if      (cum0 >= target) { which = 0; cumGE = cum0; cumAbove = excl; }
            else if (cum1 >= target) { which = 1; cumGE = cum1; cumAbove = cum0; }
            else if (cum2 >= target) { which = 2; cumGE = cum2; cumAbove = cum1; }
            else                     { which = 3; cumGE = cum3; cumAbove = cum2; }
            int pb = 255 - 4 * l - which;
            const unsigned long long bal = __ballot(cross);
            const int src = __ffsll(bal) - 1;
            pb       = __shfl(pb, src);
            cumGE    = (uint)__shfl((int)cumGE, src);
            cumAbove = (uint)__shfl((int)cumAbove, src);
            if (l == 0) {
                bc_prefix = prefix | ((uint)pb << shift);
                bc_target = target - cumAbove;
                bc_done   = ((TARGET - target) + cumGE <= MAXC) ? 1u : 0u;
            }
        }
        __syncthreads();
        prefix = bc_prefix; target = bc_target; done = bc_done;
        if (done) break;
    }

    // -------- Phase B: compact candidates (key >= prefix) --------
#pragma unroll
    for (int i = 0; i < 4; ++i) {
        if (keys[i] >= prefix) {
            const uint p = atomicAdd(&scount, 1u);
            if (p < MAXC) { cv[p] = vals[i]; cjj[p] = t * 4 + i; }
        }
    }
    flagw[t] = 0;
    __syncthreads();
    const int n = (int)min(scount, (uint)MAXC);

    // -------- Phase C: fp32 rank; decide if f64 refinement is needed --------
    if (t < 64) {
        const float myv = (t < n) ? cv[t] : -FLT_MAX;
        const int   myj = (t < n) ? cjj[t] : 0x7fffffff;
        int rank = 0;
        for (int o = 0; o < n; ++o) {
            const float ov = cv[o];
            const int   oj = cjj[o];
            rank += (ov > myv || (ov == myv && oj < myj)) ? 1 : 0;
        }
        if (t < n) {
            crank[t] = rank;
            if (rank == KSEL - 1) sh_v20 = myv;
            if (rank == KSEL)     sh_v21 = myv;
        }
    }
    __syncthreads();
    const bool amb = (sh_v20 - sh_v21 <= DELTA);   // block-uniform

    if (!amb) {
        // fast path: fp32 order is provably the f64 order at the 20/21 boundary
        if (t < n && crank[t] < KSEL) {
            sel20v[crank[t]] = cv[t];
            sel20j[crank[t]] = cjj[t];
            ((unsigned char*)flagw)[cjj[t]] = 1;
        }
    } else {
        // slow path: stage x row in f64, recompute all candidate dots, rank in f64
        sxd[t]       = (double)x[(size_t)b * IN_DIM + t];
        sxd[t + 256] = (double)x[(size_t)b * IN_DIM + t + 256];
        sxd[t + 512] = (double)x[(size_t)b * IN_DIM + t + 512];
        __syncthreads();
        {
            const int c  = t >> 2;
            const int l4 = t & 3;
            if (c < n) {
                const int j = cjj[c];
                const float* wr = We + (size_t)j * IN_DIM;
                double s0 = 0.0, s1 = 0.0, s2 = 0.0, s3 = 0.0;
#pragma unroll 4
                for (int m = 0; m < 48; ++m) {
                    const int k = l4 * 4 + 16 * m;
                    const float4 w4 = *(const float4*)&wr[k];
                    s0 = fma((double)w4.x, sxd[k],     s0);
                    s1 = fma((double)w4.y, sxd[k + 1], s1);
                    s2 = fma((double)w4.z, sxd[k + 2], s2);
                    s3 = fma((double)w4.w, sxd[k + 3], s3);
                }
                double s = (s0 + s1) + (s2 + s3);
                s += __shfl_xor(s, 1);
                s += __shfl_xor(s, 2);
                if (l4 == 0) {
                    const double v = s + (double)be[j];
                    cval[c] = v > 0.0 ? v : 0.0;
                }
            }
        }
        __syncthreads();
        if (t < 64) {
            const double myv = (t < n) ? cval[t] : -1.0;
            const int    myj = (t < n) ? cjj[t]  : 0x7fffffff;
            int rank = 0;
            for (int o = 0; o < n; ++o) {
                const double ov = cval[o];
                const int    oj = cjj[o];
                rank += (ov > myv || (ov == myv && oj < myj)) ? 1 : 0;
            }
            if (t < n && rank < KSEL) {
                sel20v[rank] = (float)myv;
                sel20j[rank] = myj;
                ((unsigned char*)flagw)[myj] = 1;
            }
        }
    }
    __syncthreads();

    // -------- Phase E: masked h write --------
    {
        const uint fw = flagw[t];
        float4 o;
        o.x = (fw & 0x000000FFu) ? vals[0] : 0.f;
        o.y = (fw & 0x0000FF00u) ? vals[1] : 0.f;
        o.z = (fw & 0x00FF0000u) ? vals[2] : 0.f;
        o.w = (fw & 0xFF000000u) ? vals[3] : 0.f;
        *(float4*)&hrow[t * 4] = o;
    }

    // -------- Phase F: sparse decode --------
    float a0 = 0.f, a1 = 0.f, a2 = 0.f;
#pragma unroll 4
    for (int s = 0; s < KSEL; ++s) {
        const float v = sel20v[s];
        const float* wr = WdT + (size_t)sel20j[s] * IN_DIM;
        a0 = fmaf(v, wr[t], a0);
        a1 = fmaf(v, wr[t + 256], a1);
        a2 = fmaf(v, wr[t + 512], a2);
    }
    float* rrow = recon + (size_t)b * IN_DIM;
    rrow[t]       = a0 + bd[t];
    rrow[t + 256] = a1 + bd[t + 256];
    rrow[t + 512] = a2 + bd[t + 512];
}

extern "C" void kernel_launch(void* const* d_in, const int* in_sizes, int n_in,
                              void* d_out, int out_size, void* d_ws, size_t ws_size,
                              hipStream_t stream)
{
    const float* x  = (const float*)d_in[0];
    const float* We = (const float*)d_in[1];
    const float* be = (const float*)d_in[2];
    const float* Wd = (const float*)d_in[3];
    const float* bd = (const float*)d_in[4];
    const int batch = in_sizes[0] / IN_DIM;   // 65536

    float* recon = (float*)d_out;
    float* h     = (float*)d_out + (size_t)batch * IN_DIM;

    const size_t WDT_BYTES = (size_t)IN_DIM * HID * sizeof(float);
    const size_t WH_BYTES  = (size_t)HID * IN_DIM * sizeof(_Float16);
    const size_t XH_BYTES  = (size_t)batch * IN_DIM * sizeof(_Float16);
    float*     WdT = (float*)d_ws;
    _Float16*  wh  = (_Float16*)((char*)d_ws + WDT_BYTES);
    _Float16*  xh  = (_Float16*)((char*)d_ws + WDT_BYTES + WH_BYTES);
    const bool mfma_ok = (ws_size >= WDT_BYTES + WH_BYTES + XH_BYTES) && (batch % 128 == 0);

    {
        dim3 g(HID / 32, IN_DIM / 32), blk(32, 8);
        k_transpose<<<g, blk, 0, stream>>>(Wd, WdT);
    }
    if (mfma_ok) {
        k_split_x<<<(int)(((size_t)batch * IN_DIM / 8) / 256), 256, 0, stream>>>(x, xh);
        k_split_w<<<(HID * IN_DIM / 8) / 256, 256, 0, stream>>>(We, wh);
        dim3 g(HID / 128, batch / 128);
        k_encode_f16<<<g, 256, 0, stream>>>(xh, wh, be, h);
    } else {
        dim3 g(HID / 128, batch / 128);
        k_encode<<<g, 256, 0, stream>>>(x, We, be, h);
    }
    k_topk_decode<<<batch, 256, 0, stream>>>(h, x, We, be, WdT, bd, recon);
}

// Round 5
// 663.891 us; speedup vs baseline: 6.0243x; 1.1484x over previous
//
#include <hip/hip_runtime.h>
#include <cstdint>
#include <cfloat>

#define IN_DIM 768
#define HID    1024
#define KSEL   20
#define MAXC   64
#define TARGET 24u
#define WSCALE 4096.0f
#define INV_WSCALE (1.0f / 4096.0f)
#define DELTA  3e-5f

typedef _Float16 f16x8 __attribute__((ext_vector_type(8)));
typedef float    f32x4 __attribute__((ext_vector_type(4)));

__device__ __forceinline__ void gload_lds16(const void* g, void* l) {
    __builtin_amdgcn_global_load_lds(
        (const __attribute__((address_space(1))) uint32_t*)g,
        (__attribute__((address_space(3))) uint32_t*)l, 16, 0, 0);
}

// ---------------- K0: transpose W_dec [768][1024] -> WdT [1024][768] ----------------
__global__ void k_transpose(const float* __restrict__ Wd, float* __restrict__ WdT) {
    __shared__ float tile[32][33];
    const int j0 = blockIdx.x * 32;
    const int i0 = blockIdx.y * 32;
    const int tx = threadIdx.x;
    const int ty = threadIdx.y;
#pragma unroll
    for (int r = 0; r < 4; ++r)
        tile[ty + r * 8][tx] = Wd[(size_t)(i0 + ty + r * 8) * HID + (j0 + tx)];
    __syncthreads();
#pragma unroll
    for (int r = 0; r < 4; ++r)
        WdT[(size_t)(j0 + ty + r * 8) * IN_DIM + (i0 + tx)] = tile[tx][ty + r * 8];
}

// ---------------- split kernels: fp32 -> fp16 (W scaled by 4096) ----------------
__global__ __launch_bounds__(256) void k_split_x(const float* __restrict__ x,
                                                 _Float16* __restrict__ xh) {
    const size_t base = ((size_t)blockIdx.x * 256 + threadIdx.x) * 8;
    const float4 a = *(const float4*)(x + base);
    const float4 b = *(const float4*)(x + base + 4);
    f16x8 o;
    o[0] = (_Float16)a.x; o[1] = (_Float16)a.y; o[2] = (_Float16)a.z; o[3] = (_Float16)a.w;
    o[4] = (_Float16)b.x; o[5] = (_Float16)b.y; o[6] = (_Float16)b.z; o[7] = (_Float16)b.w;
    *(f16x8*)(xh + base) = o;
}

__global__ __launch_bounds__(256) void k_split_w(const float* __restrict__ w,
                                                 _Float16* __restrict__ wh) {
    const size_t base = ((size_t)blockIdx.x * 256 + threadIdx.x) * 8;
    const float4 a = *(const float4*)(w + base);
    const float4 b = *(const float4*)(w + base + 4);
    f16x8 o;
    o[0] = (_Float16)(a.x * WSCALE); o[1] = (_Float16)(a.y * WSCALE);
    o[2] = (_Float16)(a.z * WSCALE); o[3] = (_Float16)(a.w * WSCALE);
    o[4] = (_Float16)(b.x * WSCALE); o[5] = (_Float16)(b.y * WSCALE);
    o[6] = (_Float16)(b.z * WSCALE); o[7] = (_Float16)(b.w * WSCALE);
    *(f16x8*)(wh + base) = o;
}

// ---------------- K1: fp16 MFMA encode  h = relu((x16 @ w16^T)/4096 + be) ----------------
__global__ __launch_bounds__(256) void k_encode_f16(
    const _Float16* __restrict__ xh, const _Float16* __restrict__ wh,
    const float* __restrict__ be, float* __restrict__ h)
{
    __shared__ _Float16 lA[128 * 64];
    __shared__ _Float16 lB[128 * 64];
    const int t   = threadIdx.x;
    const int wid = t >> 6, l = t & 63;
    const int wm  = (wid >> 1) * 64, wn = (wid & 1) * 64;
    const int bn  = blockIdx.x * 128, bm = blockIdx.y * 128;

    const int lr = l >> 3;
    const int sl = (l & 7) ^ lr;
    const _Float16* gA = xh + (size_t)(bm + wid * 32 + lr) * IN_DIM + sl * 8;
    const _Float16* gB = wh + (size_t)(bn + wid * 32 + lr) * IN_DIM + sl * 8;
    char* la0 = (char*)lA + wid * 32 * 128;
    char* lb0 = (char*)lB + wid * 32 * 128;

    f32x4 acc[4][4];
#pragma unroll
    for (int i = 0; i < 4; ++i)
#pragma unroll
        for (int j = 0; j < 4; ++j) acc[i][j] = (f32x4){0.f, 0.f, 0.f, 0.f};

    const int row16 = l & 15, kb = l >> 4;

    for (int kt = 0; kt < IN_DIM; kt += 64) {
        __syncthreads();
#pragma unroll
        for (int i = 0; i < 4; ++i) {
            gload_lds16(gA + (size_t)i * 8 * IN_DIM + kt, la0 + i * 1024);
            gload_lds16(gB + (size_t)i * 8 * IN_DIM + kt, lb0 + i * 1024);
        }
        __syncthreads();

        f16x8 af[4][2], bf[4][2];
#pragma unroll
        for (int f = 0; f < 4; ++f) {
            const int ra = wm + f * 16 + row16;
            const int pa = kb ^ (ra & 7);
            af[f][0] = *(const f16x8*)((const char*)lA + ra * 128 + pa * 16);
            af[f][1] = *(const f16x8*)((const char*)lA + ra * 128 + (pa ^ 4) * 16);
            const int rb = wn + f * 16 + row16;
            const int pb = kb ^ (rb & 7);
            bf[f][0] = *(const f16x8*)((const char*)lB + rb * 128 + pb * 16);
            bf[f][1] = *(const f16x8*)((const char*)lB + rb * 128 + (pb ^ 4) * 16);
        }
#pragma unroll
        for (int kh = 0; kh < 2; ++kh)
#pragma unroll
            for (int fm = 0; fm < 4; ++fm)
#pragma unroll
                for (int fn = 0; fn < 4; ++fn)
                    acc[fm][fn] = __builtin_amdgcn_mfma_f32_16x16x32_f16(
                        af[fm][kh], bf[fn][kh], acc[fm][fn], 0, 0, 0);
    }

    const int col = l & 15, rg = (l >> 4) * 4;
#pragma unroll
    for (int fn = 0; fn < 4; ++fn) {
        const int n = bn + wn + fn * 16 + col;
        const float bias = be[n];
#pragma unroll
        for (int fm = 0; fm < 4; ++fm) {
            const int m0 = bm + wm + fm * 16 + rg;
#pragma unroll
            for (int q = 0; q < 4; ++q)
                h[(size_t)(m0 + q) * HID + n] = fmaxf(fmaf(acc[fm][fn][q], INV_WSCALE, bias), 0.f);
        }
    }
}

// ---------------- K1-fallback: fp32 encode ----------------
__global__ __launch_bounds__(256, 2) void k_encode(
    const float* __restrict__ x, const float* __restrict__ We,
    const float* __restrict__ be, float* __restrict__ h)
{
    __shared__ float lx[16][132];
    __shared__ float lw[16][132];
    const int t  = threadIdx.x;
    const int tx = t & 15;
    const int ty = t >> 4;
    const int bn = blockIdx.x * 128;
    const int bm = blockIdx.y * 128;

    float acc[8][8];
#pragma unroll
    for (int r = 0; r < 8; ++r)
#pragma unroll
        for (int c = 0; c < 8; ++c) acc[r][c] = 0.f;

    const int sk = t & 15;
    const int sm = t >> 4;

    for (int kt = 0; kt < IN_DIM; kt += 16) {
        __syncthreads();
#pragma unroll
        for (int p = 0; p < 8; ++p) {
            const int m = sm + p * 16;
            lx[sk][m] = x [(size_t)(bm + m) * IN_DIM + (kt + sk)];
            lw[sk][m] = We[(size_t)(bn + m) * IN_DIM + (kt + sk)];
        }
        __syncthreads();
#pragma unroll
        for (int kk = 0; kk < 16; ++kk) {
            const float4 xa = *(const float4*)&lx[kk][ty * 8];
            const float4 xb = *(const float4*)&lx[kk][ty * 8 + 4];
            const float4 wa = *(const float4*)&lw[kk][tx * 4];
            const float4 wb = *(const float4*)&lw[kk][tx * 4 + 64];
            const float xf[8] = {xa.x, xa.y, xa.z, xa.w, xb.x, xb.y, xb.z, xb.w};
            const float wf[8] = {wa.x, wa.y, wa.z, wa.w, wb.x, wb.y, wb.z, wb.w};
#pragma unroll
            for (int r = 0; r < 8; ++r)
#pragma unroll
                for (int c = 0; c < 8; ++c)
                    acc[r][c] = fmaf(xf[r], wf[c], acc[r][c]);
        }
    }
#pragma unroll
    for (int r = 0; r < 8; ++r) {
        const size_t row = (size_t)(bm + ty * 8 + r) * HID;
#pragma unroll
        for (int c = 0; c < 4; ++c) {
            h[row + bn + tx * 4 + c]      = fmaxf(acc[r][c]     + be[bn + tx * 4 + c], 0.f);
            h[row + bn + 64 + tx * 4 + c] = fmaxf(acc[r][c + 4] + be[bn + 64 + tx * 4 + c], 0.f);
        }
    }
}

// ---------------- K2: wave-per-row top-k -> lazy f64 refine -> mask + sparse decode ----------------
// 4 rows / 256-thread block, one 64-lane wave per row. NO __syncthreads:
// all cross-lane traffic is wave-local (LDS per-wave segments + shuffles);
// __builtin_amdgcn_wave_barrier() pins ordering at LDS handoffs.
__global__ __launch_bounds__(256) void k_topk_decode(
    float* __restrict__ h,
    const float* __restrict__ x,  const float* __restrict__ We,
    const float* __restrict__ be,
    const float* __restrict__ WdT, const float* __restrict__ bd,
    float* __restrict__ recon)
{
    const int wid  = threadIdx.x >> 6;
    const int lane = threadIdx.x & 63;
    const int b    = blockIdx.x * 4 + wid;
    float* hrow = h + (size_t)b * HID;

    __shared__ uint   hist[4][256];
    __shared__ float  cvF [4][MAXC];
    __shared__ int    cjL [4][MAXC];
    __shared__ double cvD [4][MAXC];
    __shared__ float  selv[4][KSEL];
    __shared__ int    selj[4][KSEL];
    __shared__ float  xrow[4][IN_DIM];

    // ---- load 16 h values per lane (coalesced float4 at element lane*4 + q*256) ----
    float vals[4][4];
    uint  keys[4][4];
#pragma unroll
    for (int q = 0; q < 4; ++q) {
        const float4 v4 = *(const float4*)&hrow[q * 256 + lane * 4];
        vals[q][0] = v4.x; vals[q][1] = v4.y; vals[q][2] = v4.z; vals[q][3] = v4.w;
#pragma unroll
        for (int i = 0; i < 4; ++i) keys[q][i] = __float_as_uint(vals[q][i]); // h>=0 monotone
    }

    // ---- Phase A: wave-local radix threshold: 24 <= count(key >= prefix) <= 64 ----
    uint prefix = 0, target = TARGET;
    int done = 0;
    for (int level = 0; level < 4 && !done; ++level) {
        const int  shift = 24 - 8 * level;
        const uint pmask = (level == 0) ? 0u : (0xFFFFFFFFu << (shift + 8));
        *(uint4*)&hist[wid][lane * 4] = (uint4){0u, 0u, 0u, 0u};
        __builtin_amdgcn_wave_barrier();
#pragma unroll
        for (int q = 0; q < 4; ++q)
#pragma unroll
            for (int i = 0; i < 4; ++i)
                if ((keys[q][i] & pmask) == prefix)
                    atomicAdd(&hist[wid][(keys[q][i] >> shift) & 0xFF], 1u);
        __builtin_amdgcn_wave_barrier();
        const uint4 hb = *(const uint4*)&hist[wid][252 - 4 * lane];
        const uint c0 = hb.w, c1 = hb.z, c2 = hb.y, c3 = hb.x;   // descending bins
        const uint slc = c0 + c1 + c2 + c3;
        uint inc = slc;
#pragma unroll
        for (int off = 1; off < 64; off <<= 1) {
            const uint o = __shfl_up(inc, off);
            if (lane >= off) inc += o;
        }
        const uint excl = inc - slc;
        const uint cum0 = excl + c0, cum1 = cum0 + c1, cum2 = cum1 + c2, cum3 = cum2 + c3;
        const bool cross = (excl < target) && (cum3 >= target);
        int which; uint cumGE, cumAbove;
        if      (cum0 >= target) { which = 0; cumGE = cum0; cumAbove = excl; }
        else if (cum1 >= target) { which = 1; cumGE = cum1; cumAbove = cum0; }
        else if (cum2 >= target) { which = 2; cumGE = cum2; cumAbove = cum1; }
        else                     { which = 3; cumGE = cum3; cumAbove = cum2; }
        int pb = 255 - 4 * lane - which;
        const unsigned long long bal = __ballot(cross);
        const int src = __ffsll(bal) - 1;
        pb       = __shfl(pb, src);
        cumGE    = (uint)__shfl((int)cumGE, src);
        cumAbove = (uint)__shfl((int)cumAbove, src);
        prefix  |= ((uint)pb << shift);
        target  -= cumAbove;
        done     = ((TARGET - target) + cumGE <= MAXC) ? 1 : 0;
        __builtin_amdgcn_wave_barrier();
    }

    // ---- Phase B: compact candidates via shuffle prefix-sum (deterministic order) ----
    uint cnt = 0;
#pragma unroll
    for (int q = 0; q < 4; ++q)
#pragma unroll
        for (int i = 0; i < 4; ++i) cnt += (keys[q][i] >= prefix) ? 1u : 0u;
    uint inc = cnt;
#pragma unroll
    for (int off = 1; off < 64; off <<= 1) {
        const uint o = __shfl_up(inc, off);
        if (lane >= off) inc += o;
    }
    const uint base = inc - cnt;
    const int  n    = min((int)__shfl((int)inc, 63), MAXC);
    {
        uint m = 0;
#pragma unroll
        for (int q = 0; q < 4; ++q)
#pragma unroll
            for (int i = 0; i < 4; ++i)
                if (keys[q][i] >= prefix) {
                    const uint slot = base + m; ++m;
                    if (slot < MAXC) {
                        cvF[wid][slot] = vals[q][i];
                        cjL[wid][slot] = q * 256 + lane * 4 + i;
                    }
                }
    }
    __builtin_amdgcn_wave_barrier();

    // ---- Phase C: fp32 rank over candidates (all 64 lanes) ----
    const float myv = (lane < n) ? cvF[wid][lane] : -FLT_MAX;
    const int   myj = (lane < n) ? cjL[wid][lane] : 0x7fffffff;
    int rank = 0;
    for (int o = 0; o < n; ++o) {
        const float ov = cvF[wid][o];
        const int   oj = cjL[wid][o];
        rank += (ov > myv || (ov == myv && oj < myj)) ? 1 : 0;
    }
    const unsigned long long b19 = __ballot(lane < n && rank == KSEL - 1);
    const unsigned long long b20 = __ballot(lane < n && rank == KSEL);
    const float v20 = b19 ? __shfl(myv, __ffsll(b19) - 1) : 0.f;
    const float v21 = b20 ? __shfl(myv, __ffsll(b20) - 1) : -1e9f;
    const bool  amb = (b20 != 0ull) && (v20 - v21 <= DELTA);

    unsigned long long selm;
    if (!amb) {
        // fast path: fp32 order is the true order at the 20/21 boundary
        if (lane < n && rank < KSEL) { selv[wid][rank] = myv; selj[wid][rank] = myj; }
        selm = __ballot(lane < n && rank < KSEL);
    } else {
        // slow path: f64 recompute of candidate dots, rank in f64
#pragma unroll
        for (int q = 0; q < 12; ++q)
            xrow[wid][lane + 64 * q] = x[(size_t)b * IN_DIM + lane + 64 * q];
        __builtin_amdgcn_wave_barrier();
        const int l4 = lane & 3;
#pragma unroll 1
        for (int p = 0; p < 4; ++p) {
            const int c = p * 16 + (lane >> 2);
            if (c < n) {
                const int j = cjL[wid][c];
                const float* wr = We + (size_t)j * IN_DIM;
                double s0 = 0.0, s1 = 0.0, s2 = 0.0, s3 = 0.0;
#pragma unroll 4
                for (int m = 0; m < 48; ++m) {
                    const int k = l4 * 4 + 16 * m;
                    const float4 w4 = *(const float4*)&wr[k];
                    s0 = fma((double)w4.x, (double)xrow[wid][k],     s0);
                    s1 = fma((double)w4.y, (double)xrow[wid][k + 1], s1);
                    s2 = fma((double)w4.z, (double)xrow[wid][k + 2], s2);
                    s3 = fma((double)w4.w, (double)xrow[wid][k + 3], s3);
                }
                double s = (s0 + s1) + (s2 + s3);
                s += __shfl_xor(s, 1);
                s += __shfl_xor(s, 2);
                if (l4 == 0) {
                    const double v = s + (double)be[j];
                    cvD[wid][c] = v > 0.0 ? v : 0.0;
                }
            }
        }
        __builtin_amdgcn_wave_barrier();
        const double myd = (lane < n) ? cvD[wid][lane] : -1.0;
        int rk = 0;
        for (int o = 0; o < n; ++o) {
            const double ov = cvD[wid][o];
            const int   oj = cjL[wid][o];
            rk += (ov > myd || (ov == myd && oj < myj)) ? 1 : 0;
        }
        if (lane < n && rk < KSEL) { selv[wid][rk] = (float)myd; selj[wid][rk] = myj; }
        selm = __ballot(lane < n && rk < KSEL);
    }
    __builtin_amdgcn_wave_barrier();

    // ---- Phase D: masked h write (recompute slot order -> ballot bit test) ----
    {
        uint m = 0;
#pragma unroll
        for (int q = 0; q < 4; ++q) {
            float4 o;
            float ov[4];
#pragma unroll
            for (int i = 0; i < 4; ++i) {
                bool keep = false;
                if (keys[q][i] >= prefix) {
                    const uint slot = base + m; ++m;
                    keep = (slot < MAXC) && ((selm >> slot) & 1ull);
                }
                ov[i] = keep ? vals[q][i] : 0.f;
            }
            o.x = ov[0]; o.y = ov[1]; o.z = ov[2]; o.w = ov[3];
            *(float4*)&hrow[q * 256 + lane * 4] = o;
        }
    }

    // ---- Phase E: sparse decode, float4 lanes ----
    f32x4 a0 = {0.f,0.f,0.f,0.f}, a1 = {0.f,0.f,0.f,0.f}, a2 = {0.f,0.f,0.f,0.f};
#pragma unroll 4
    for (int s = 0; s < KSEL; ++s) {
        const float v = selv[wid][s];
        const float* wr = WdT + (size_t)selj[wid][s] * IN_DIM;
        const float4 w0 = *(const float4*)&wr[lane * 4];
        const float4 w1 = *(const float4*)&wr[lane * 4 + 256];
        const float4 w2 = *(const float4*)&wr[lane * 4 + 512];
        a0[0] = fmaf(v, w0.x, a0[0]); a0[1] = fmaf(v, w0.y, a0[1]);
        a0[2] = fmaf(v, w0.z, a0[2]); a0[3] = fmaf(v, w0.w, a0[3]);
        a1[0] = fmaf(v, w1.x, a1[0]); a1[1] = fmaf(v, w1.y, a1[1]);
        a1[2] = fmaf(v, w1.z, a1[2]); a1[3] = fmaf(v, w1.w, a1[3]);
        a2[0] = fmaf(v, w2.x, a2[0]); a2[1] = fmaf(v, w2.y, a2[1]);
        a2[2] = fmaf(v, w2.z, a2[2]); a2[3] = fmaf(v, w2.w, a2[3]);
    }
    float* rrow = recon + (size_t)b * IN_DIM;
    const float4 bd0 = *(const float4*)&bd[lane * 4];
    const float4 bd1 = *(const float4*)&bd[lane * 4 + 256];
    const float4 bd2 = *(const float4*)&bd[lane * 4 + 512];
    *(float4*)&rrow[lane * 4]       = (float4){a0[0] + bd0.x, a0[1] + bd0.y, a0[2] + bd0.z, a0[3] + bd0.w};
    *(float4*)&rrow[lane * 4 + 256] = (float4){a1[0] + bd1.x, a1[1] + bd1.y, a1[2] + bd1.z, a1[3] + bd1.w};
    *(float4*)&rrow[lane * 4 + 512] = (float4){a2[0] + bd2.x, a2[1] + bd2.y, a2[2] + bd2.z, a2[3] + bd2.w};
}

extern "C" void kernel_launch(void* const* d_in, const int* in_sizes, int n_in,
                              void* d_out, int out_size, void* d_ws, size_t ws_size,
                              hipStream_t stream)
{
    const float* x  = (const float*)d_in[0];
    const float* We = (const float*)d_in[1];
    const float* be = (const float*)d_in[2];
    const float* Wd = (const float*)d_in[3];
    const float* bd = (const float*)d_in[4];
    const int batch = in_sizes[0] / IN_DIM;   // 65536

    float* recon = (float*)d_out;
    float* h     = (float*)d_out + (size_t)batch * IN_DIM;

    const size_t WDT_BYTES = (size_t)IN_DIM * HID * sizeof(float);
    const size_t WH_BYTES  = (size_t)HID * IN_DIM * sizeof(_Float16);
    const size_t XH_BYTES  = (size_t)batch * IN_DIM * sizeof(_Float16);
    float*     WdT = (float*)d_ws;
    _Float16*  wh  = (_Float16*)((char*)d_ws + WDT_BYTES);
    _Float16*  xh  = (_Float16*)((char*)d_ws + WDT_BYTES + WH_BYTES);
    const bool mfma_ok = (ws_size >= WDT_BYTES + WH_BYTES + XH_BYTES) && (batch % 128 == 0);

    {
        dim3 g(HID / 32, IN_DIM / 32), blk(32, 8);
        k_transpose<<<g, blk, 0, stream>>>(Wd, WdT);
    }
    if (mfma_ok) {
        k_split_x<<<(int)(((size_t)batch * IN_DIM / 8) / 256), 256, 0, stream>>>(x, xh);
        k_split_w<<<(HID * IN_DIM / 8) / 256, 256, 0, stream>>>(We, wh);
        dim3 g(HID / 128, batch / 128);
        k_encode_f16<<<g, 256, 0, stream>>>(xh, wh, be, h);
    } else {
        dim3 g(HID / 128, batch / 128);
        k_encode<<<g, 256, 0, stream>>>(x, We, be, h);
    }
    k_topk_decode<<<batch / 4, 256, 0, stream>>>(h, x, We, be, WdT, bd, recon);
}